// Round 11
// baseline (347.997 us; speedup 1.0000x reference)
//
#include <hip/hip_runtime.h>

typedef __bf16 bf16x8 __attribute__((ext_vector_type(8)));
typedef float f32x4 __attribute__((ext_vector_type(4)));
typedef unsigned short ushort8 __attribute__((ext_vector_type(8)));
typedef unsigned short u16;

#define MFMA16(a, b, c) __builtin_amdgcn_mfma_f32_16x16x32_bf16(a, b, c, 0, 0, 0)
#define FENCE() __builtin_amdgcn_sched_barrier(0)
#define BARRIER() do { FENCE(); __builtin_amdgcn_s_barrier(); FENCE(); } while (0)
#define VMCNT(n) do { asm volatile("s_waitcnt vmcnt(" #n ")"); FENCE(); } while (0)

__device__ __forceinline__ u16 f2bf(float v) {
  unsigned int u = __builtin_bit_cast(unsigned int, v);
  u += 0x7fffu + ((u >> 16) & 1u);   // RNE; inputs are finite
  return (u16)(u >> 16);
}

__device__ __forceinline__ void gload16(const u16* g, u16* l) {
  __builtin_amdgcn_global_load_lds((__attribute__((address_space(1))) void*)(g),
                                   (__attribute__((address_space(3))) void*)(l), 16, 0, 0);
}

// ---------------- fused prep: x->bf16, Wqkv^T, Wout^T, agent*scale ----------------
__global__ __launch_bounds__(256) void prep(const float* __restrict__ x, u16* __restrict__ x_bf,
                                            const float* __restrict__ Wqkv, u16* __restrict__ wqkvT,
                                            const float* __restrict__ Wout, u16* __restrict__ woutT,
                                            const float* __restrict__ agent, u16* __restrict__ a_bf) {
  __shared__ float tile[64][65];
  int bid = blockIdx.x;
  int t = threadIdx.x;
  if (bid < 8192) {
    size_t i = (size_t)bid * 256 + t;
    const float4* p = (const float4*)x + i * 2;
    float4 a = p[0], b = p[1];
    ushort8 o;
    o[0] = f2bf(a.x); o[1] = f2bf(a.y); o[2] = f2bf(a.z); o[3] = f2bf(a.w);
    o[4] = f2bf(b.x); o[5] = f2bf(b.y); o[6] = f2bf(b.z); o[7] = f2bf(b.w);
    *((ushort8*)x_bf + i) = o;
    return;
  }
  if (bid >= 9216) {
    int i = (bid - 9216) * 256 + t;
    a_bf[i] = f2bf(agent[i] * 0.125f);
    return;
  }
  const float* W; u16* WT; int K = 1024, N; int b2;
  if (bid < 8960) { W = Wqkv; WT = wqkvT; N = 3072; b2 = bid - 8192; }
  else            { W = Wout; WT = woutT; N = 1024; b2 = bid - 8960; }
  int nt = N >> 6;
  int kt = b2 / nt, nti = b2 - kt * nt;
  int k0 = kt << 6, n0 = nti << 6;
  int r = t >> 4, c4 = (t & 15) << 2;
#pragma unroll
  for (int j = 0; j < 4; ++j) {
    float4 v = *(const float4*)&W[(size_t)(k0 + j * 16 + r) * N + n0 + c4];
    tile[j * 16 + r][c4] = v.x; tile[j * 16 + r][c4 + 1] = v.y;
    tile[j * 16 + r][c4 + 2] = v.z; tile[j * 16 + r][c4 + 3] = v.w;
  }
  __syncthreads();
  int rn = t >> 2, cs = (t & 3) << 4;
  ushort8 o0, o1;
#pragma unroll
  for (int e = 0; e < 8; ++e) { o0[e] = f2bf(tile[cs + e][rn]); o1[e] = f2bf(tile[cs + 8 + e][rn]); }
  u16* dst = WT + (size_t)(n0 + rn) * K + k0 + cs;
  *(ushort8*)dst = o0;
  *(ushort8*)(dst + 8) = o1;
}

// ---------------- 256^2 GEMM, r7 schedule + B-fragments direct from L2 (no B staging) ----------------
// 512 thr = 8 waves (2Mx4N), per-wave C = 128x64. BK=32. LDS: A-ring 4 slots x 16KB = 64KB.
// Per tile: PH_EVEN { bar; ds_read A_HI(t); stage A(t+3); gload B-frags(t+1); MFMA lo }
//           PH_ODD  { vmcnt(6); bar; ds_read A_LO(t+1); MFMA hi }.
// B (6MB/2MB) is L2/L3-resident; per-lane 16B frag loads form 64B lines per li.
// LDS traffic/tile: 131KB -> ~80KB (the binding resource per m134 arithmetic).
// MODE 0: q,k -> (b,h,n,d); v -> vt (b,h,d,n) via 128KB LDS bounce. MODE 1: f32 out.
template <int MODE>
__global__ __launch_bounds__(512, 2) void gemm256(const u16* __restrict__ A, const u16* __restrict__ BT,
                                                  int M, int N, int K,
                                                  u16* __restrict__ qb, u16* __restrict__ kb,
                                                  u16* __restrict__ vt, float* __restrict__ outf) {
  extern __shared__ char smem[];   // 131072 allocated; K-loop uses first 65536
  const int NT = K >> 5;           // 32
  int ntiles = N >> 8;
  int nwg = (M >> 8) * ntiles;
  int bid = blockIdx.x;
  int wg = (bid & 7) * (nwg >> 3) + (bid >> 3);   // XCD swizzle; nwg % 8 == 0
  int tm = wg / ntiles, tn = wg - tm * ntiles;
  int rb = tm << 8, cb = tn << 8;
  int t = threadIdx.x;
  int w = t >> 6, lane = t & 63, li = lane & 15, lg = lane >> 4;
  int wr = w >> 2, wc = w & 3;

  const u16* srcA[2];
#pragma unroll
  for (int j = 0; j < 2; ++j) {
    int D = j * 8192 + t * 16;
    int L = D ^ (((D >> 7) & 3) << 4);
    int row = L >> 6, inb = L & 63;
    srcA[j] = A + (size_t)(rb + row) * K + (inb >> 1);
  }
#define STAGE_A(slot, kt) do { \
    gload16(srcA[0] + (kt) * 32, (u16*)(smem + (slot) * 16384 + t * 16)); \
    gload16(srcA[1] + (kt) * 32, (u16*)(smem + (slot) * 16384 + 8192 + t * 16)); } while (0)

  // B-fragment global pointers (per-lane); frag n row = cb + wc*64 + n*16 + li, cols tile*32 + lg*8
  const u16* bptr[4];
#pragma unroll
  for (int n = 0; n < 4; ++n)
    bptr[n] = BT + (size_t)(cb + wc * 64 + n * 16 + li) * K + lg * 8;
#define LDB(dst, tt) do { \
    dst[0] = *(const bf16x8*)(bptr[0] + (tt) * 32); \
    dst[1] = *(const bf16x8*)(bptr[1] + (tt) * 32); \
    dst[2] = *(const bf16x8*)(bptr[2] + (tt) * 32); \
    dst[3] = *(const bf16x8*)(bptr[3] + (tt) * 32); } while (0)

  int offA[8];
#pragma unroll
  for (int m8 = 0; m8 < 8; ++m8) {
    int row = wr * 128 + m8 * 16 + li;
    int L = row * 64 + lg * 16;
    offA[m8] = L ^ (((L >> 7) & 3) << 4);
  }

  f32x4 acc[8][4];
#pragma unroll
  for (int m = 0; m < 8; ++m)
#pragma unroll
    for (int n = 0; n < 4; ++n) acc[m][n] = (f32x4){0.f, 0.f, 0.f, 0.f};

  bf16x8 aF[4], aS[4], b0[4], b1[4];

#define RD_A_LO(sb, d) do { d[0] = *(const bf16x8*)((sb) + offA[0]); d[1] = *(const bf16x8*)((sb) + offA[1]); \
                            d[2] = *(const bf16x8*)((sb) + offA[2]); d[3] = *(const bf16x8*)((sb) + offA[3]); } while (0)
#define RD_A_HI(sb, d) do { d[0] = *(const bf16x8*)((sb) + offA[4]); d[1] = *(const bf16x8*)((sb) + offA[5]); \
                            d[2] = *(const bf16x8*)((sb) + offA[6]); d[3] = *(const bf16x8*)((sb) + offA[7]); } while (0)

#define PH_EVEN(t, BC, BN, STG, LDBN) do { \
    BARRIER(); \
    { char* sb_ = smem + ((t) & 3) * 16384; RD_A_HI(sb_, aS); } \
    if (STG) STAGE_A(((t) + 3) & 3, (t) + 3); \
    if (LDBN) LDB(BN, (t) + 1); \
    FENCE(); \
    __builtin_amdgcn_s_setprio(1); \
    _Pragma("unroll") for (int m = 0; m < 4; ++m) \
      _Pragma("unroll") for (int n = 0; n < 4; ++n) acc[m][n] = MFMA16(aF[m], BC[n], acc[m][n]); \
    __builtin_amdgcn_s_setprio(0); \
  } while (0)

#define PH_ODD(t, BC, RDNEXT, WAITOP) do { \
    WAITOP; \
    BARRIER(); \
    if (RDNEXT) { char* sb_ = smem + (((t) + 1) & 3) * 16384; RD_A_LO(sb_, aF); } \
    FENCE(); \
    __builtin_amdgcn_s_setprio(1); \
    _Pragma("unroll") for (int m = 0; m < 4; ++m) \
      _Pragma("unroll") for (int n = 0; n < 4; ++n) acc[4 + m][n] = MFMA16(aS[m], BC[n], acc[4 + m][n]); \
    __builtin_amdgcn_s_setprio(0); \
  } while (0)

#define TILE(t, BC, BN, STG, LDBN, RDNEXT, WAITOP) do { \
    PH_EVEN(t, BC, BN, STG, LDBN); \
    PH_ODD(t, BC, RDNEXT, WAITOP); \
  } while (0)

  // prologue: stage A tiles 0,1,2 (6 loads) + B(0) (4 loads); drain A(0)
  STAGE_A(0, 0);
  STAGE_A(1, 1);
  STAGE_A(2, 2);
  LDB(b0, 0);
  VMCNT(8);
  BARRIER();
  RD_A_LO(smem, aF);

  // main: tiles 0..NT-5 (NT=32 -> 0..27); steady VMCNT(6) keeps {A(t+2),A(t+3),B(t+1)} in flight
  for (int tt = 0; tt <= NT - 5; tt += 2) {
    TILE(tt,     b0, b1, 1, 1, 1, VMCNT(6));
    TILE(tt + 1, b1, b0, 1, 1, 1, VMCNT(6));
  }
  TILE(NT - 4, b0, b1, 1, 1, 1, VMCNT(6));   // stages A(NT-1), loads B(NT-3)
  TILE(NT - 3, b1, b0, 0, 1, 1, VMCNT(6));   // loads B(NT-2)
  TILE(NT - 2, b0, b1, 0, 1, 1, VMCNT(4));   // loads B(NT-1); A(NT-1) drained via FIFO
  TILE(NT - 1, b1, b0, 0, 0, 0, ((void)0));

  if (MODE == 0) {
    int col0 = cb + wc * 64;
    int s = col0 >> 10;                 // block-uniform (cb 256-aligned)
    int hh = (col0 >> 6) & 15;
    if (s < 2) {
      u16* dst = (s == 0) ? qb : kb;
#pragma unroll
      for (int m = 0; m < 8; ++m) {
        int rbase = rb + wr * 128 + m * 16 + lg * 4;
#pragma unroll
        for (int r = 0; r < 4; ++r) {
          int rr = rbase + r;
          size_t o = (((size_t)(rr >> 12) * 16 + hh) * 4096 + (rr & 4095)) * 64;
#pragma unroll
          for (int n = 0; n < 4; ++n) dst[o + n * 16 + li] = f2bf(acc[m][n][r]);
        }
      }
    } else {
      // V tile 256x256 bf16 = 128KB: bounce through LDS (col-major, swizzled), store coalesced.
      BARRIER();   // K-loop LDS reads done everywhere before overwrite
#pragma unroll
      for (int m = 0; m < 8; ++m) {
        int rl = wr * 128 + m * 16 + lg * 4;
#pragma unroll
        for (int n = 0; n < 4; ++n) {
          int colL = wc * 64 + n * 16 + li;
          unsigned int lo = (unsigned int)f2bf(acc[m][n][0]) | ((unsigned int)f2bf(acc[m][n][1]) << 16);
          unsigned int hi = (unsigned int)f2bf(acc[m][n][2]) | ((unsigned int)f2bf(acc[m][n][3]) << 16);
          int byte = (colL * 512 + rl * 2) ^ ((colL & 7) << 4);
          *(uint2*)(smem + byte) = make_uint2(lo, hi);
        }
      }
      BARRIER();
      int bb = rb >> 12, nnb = rb & 4095;
      int hh0b = (cb >> 6) & 15;
#pragma unroll
      for (int it = 0; it < 16; ++it) {
        int c = (it & 3) * 64 + w * 8 + (lane >> 3);     // col 0..255
        int k = (it >> 2) * 8 + (lane & 7);              // 16B row-chunk 0..31
        int kk = (k & ~7) | ((k & 7) ^ (c & 7));         // un-swizzle chunk
        uint4 v = *(const uint4*)(smem + c * 512 + kk * 16);
        size_t off = (((size_t)bb * 16 + hh0b + (c >> 6)) * 64 + (c & 63)) * 4096 + nnb + k * 8;
        *(uint4*)(vt + off) = v;
      }
    }
  } else {
#pragma unroll
    for (int m = 0; m < 8; ++m) {
#pragma unroll
      for (int r = 0; r < 4; ++r) {
        float* po = outf + (size_t)(rb + wr * 128 + m * 16 + lg * 4 + r) * N + cb + wc * 64;
#pragma unroll
        for (int n = 0; n < 4; ++n) po[n * 16 + li] = acc[m][n][r];
      }
    }
  }
#undef TILE
#undef PH_ODD
#undef PH_EVEN
#undef RD_A_LO
#undef RD_A_HI
#undef LDB
#undef STAGE_A
}

// ---------------- agent<-key flash attention (softmax over n), 8-way n-split ----------------
__global__ __launch_bounds__(256) void ak_flash(const u16* __restrict__ kb, const u16* __restrict__ vt,
                                                const u16* __restrict__ ab,
                                                float* __restrict__ pO, float* __restrict__ pM,
                                                float* __restrict__ pL) {
  __shared__ u16 p_lds[128][136];
  int bid = blockIdx.x;
  int s = bid & 7;
  int bh = bid >> 3;
  int h = bh & 15;
  int t = threadIdx.x, w = t >> 6, l = t & 63, lg = l >> 4, li = l & 15;
  int jb = w * 32;

  bf16x8 afr[2][2];
#pragma unroll
  for (int jt = 0; jt < 2; ++jt)
#pragma unroll
    for (int kk = 0; kk < 2; ++kk)
      afr[jt][kk] = *(const bf16x8*)&ab[(size_t)(h * 128 + jb + jt * 16 + li) * 64 + kk * 32 + lg * 8];

  f32x4 O[2][4];
  float mrow[2][4], lrow[2][4];
#pragma unroll
  for (int jt = 0; jt < 2; ++jt) {
#pragma unroll
    for (int dt = 0; dt < 4; ++dt) O[jt][dt] = (f32x4){0.f, 0.f, 0.f, 0.f};
#pragma unroll
    for (int r = 0; r < 4; ++r) { mrow[jt][r] = -1e30f; lrow[jt][r] = 0.f; }
  }
  const u16* kbase = kb + (size_t)bh * 4096 * 64;
  const u16* vbase = vt + (size_t)bh * 64 * 4096;

  for (int c = 0; c < 4; ++c) {
    int i0 = s * 512 + c * 128;
    f32x4 sf[2][8];
#pragma unroll
    for (int jt = 0; jt < 2; ++jt)
#pragma unroll
      for (int it = 0; it < 8; ++it) sf[jt][it] = (f32x4){0.f, 0.f, 0.f, 0.f};
#pragma unroll
    for (int it = 0; it < 8; ++it)
#pragma unroll
      for (int kk = 0; kk < 2; ++kk) {
        bf16x8 bfr = *(const bf16x8*)&kbase[(size_t)(i0 + it * 16 + li) * 64 + kk * 32 + lg * 8];
        sf[0][it] = MFMA16(afr[0][kk], bfr, sf[0][it]);
        sf[1][it] = MFMA16(afr[1][kk], bfr, sf[1][it]);
      }
#pragma unroll
    for (int jt = 0; jt < 2; ++jt)
#pragma unroll
      for (int r = 0; r < 4; ++r) {
        float cm = sf[jt][0][r];
#pragma unroll
        for (int it = 1; it < 8; ++it) cm = fmaxf(cm, sf[jt][it][r]);
#pragma unroll
        for (int off = 1; off < 16; off <<= 1) cm = fmaxf(cm, __shfl_xor(cm, off));
        float mold = mrow[jt][r];
        float mnew = fmaxf(mold, cm);
        float scale = __expf(mold - mnew);
        float ss = 0.f;
#pragma unroll
        for (int it = 0; it < 8; ++it) {
          float p = __expf(sf[jt][it][r] - mnew);
          sf[jt][it][r] = p;
          ss += p;
        }
#pragma unroll
        for (int off = 1; off < 16; off <<= 1) ss += __shfl_xor(ss, off);
        lrow[jt][r] = lrow[jt][r] * scale + ss;
        mrow[jt][r] = mnew;
#pragma unroll
        for (int dt = 0; dt < 4; ++dt) O[jt][dt][r] *= scale;
      }
#pragma unroll
    for (int jt = 0; jt < 2; ++jt)
#pragma unroll
      for (int it = 0; it < 8; ++it)
#pragma unroll
        for (int r = 0; r < 4; ++r)
          p_lds[jb + jt * 16 + lg * 4 + r][it * 16 + li] = f2bf(sf[jt][it][r]);
#pragma unroll
    for (int ks = 0; ks < 4; ++ks) {
      bf16x8 pa0 = *(const bf16x8*)&p_lds[jb + li][ks * 32 + lg * 8];
      bf16x8 pa1 = *(const bf16x8*)&p_lds[jb + 16 + li][ks * 32 + lg * 8];
#pragma unroll
      for (int dt = 0; dt < 4; ++dt) {
        bf16x8 bv = *(const bf16x8*)&vbase[(size_t)(dt * 16 + li) * 4096 + i0 + ks * 32 + lg * 8];
        O[0][dt] = MFMA16(pa0, bv, O[0][dt]);
        O[1][dt] = MFMA16(pa1, bv, O[1][dt]);
      }
    }
  }
  size_t pb = ((size_t)bh * 8 + s) * 128;
#pragma unroll
  for (int jt = 0; jt < 2; ++jt)
#pragma unroll
    for (int dt = 0; dt < 4; ++dt)
#pragma unroll
      for (int r = 0; r < 4; ++r) {
        int j = jb + jt * 16 + lg * 4 + r;
        pO[(pb + j) * 64 + dt * 16 + li] = O[jt][dt][r];
      }
  if (li == 0) {
#pragma unroll
    for (int jt = 0; jt < 2; ++jt)
#pragma unroll
      for (int r = 0; r < 4; ++r) {
        int j = jb + jt * 16 + lg * 4 + r;
        pM[pb + j] = mrow[jt][r];
        pL[pb + j] = lrow[jt][r];
      }
  }
}

// combine split partials -> out1t (bh, d, j). grid 64*8 (bh x d-chunk), 128 thr (j).
__global__ __launch_bounds__(128) void ak_combine(const float* __restrict__ pO, const float* __restrict__ pM,
                                                  const float* __restrict__ pL, u16* __restrict__ out1t) {
  int bh = blockIdx.x >> 3, dc = blockIdx.x & 7;
  int j = threadIdx.x;
  float ms[8], wv[8];
  float M = -1e30f;
#pragma unroll
  for (int s = 0; s < 8; ++s) { ms[s] = pM[((size_t)bh * 8 + s) * 128 + j]; M = fmaxf(M, ms[s]); }
  float L = 0.f;
#pragma unroll
  for (int s = 0; s < 8; ++s) { wv[s] = __expf(ms[s] - M); L += wv[s] * pL[((size_t)bh * 8 + s) * 128 + j]; }
  float inv = 1.f / L;
  float4 A = {0.f, 0.f, 0.f, 0.f}, B = {0.f, 0.f, 0.f, 0.f};
#pragma unroll
  for (int s = 0; s < 8; ++s) {
    const float4* p = (const float4*)&pO[(((size_t)bh * 8 + s) * 128 + j) * 64 + dc * 8];
    float4 x = p[0], y = p[1];
    A.x += wv[s] * x.x; A.y += wv[s] * x.y; A.z += wv[s] * x.z; A.w += wv[s] * x.w;
    B.x += wv[s] * y.x; B.y += wv[s] * y.y; B.z += wv[s] * y.z; B.w += wv[s] * y.w;
  }
  size_t ob = ((size_t)bh * 64 + dc * 8) * 128 + j;
  out1t[ob + 0 * 128] = f2bf(A.x * inv);
  out1t[ob + 1 * 128] = f2bf(A.y * inv);
  out1t[ob + 2 * 128] = f2bf(A.z * inv);
  out1t[ob + 3 * 128] = f2bf(A.w * inv);
  out1t[ob + 4 * 128] = f2bf(B.x * inv);
  out1t[ob + 5 * 128] = f2bf(B.y * inv);
  out1t[ob + 6 * 128] = f2bf(B.z * inv);
  out1t[ob + 7 * 128] = f2bf(B.w * inv);
}

// ---------------- q<-agent attention fused with P@out1 ----------------
__global__ __launch_bounds__(256) void qa_fused(const u16* __restrict__ qb, const u16* __restrict__ out1t,
                                                const u16* __restrict__ ab, u16* __restrict__ out2) {
  __shared__ u16 p_lds[128][136];
  int bid = blockIdx.x;
  int nt = bid & 31;
  int bh = bid >> 5;
  int h = bh & 15, b = bh >> 4;
  int t = threadIdx.x, w = t >> 6, l = t & 63, lg = l >> 4, li = l & 15;
  int n0 = nt * 128;

  const u16* qbase = qb + ((size_t)bh * 4096 + n0 + w * 32) * 64;
  bf16x8 qf[2][2];
#pragma unroll
  for (int rt = 0; rt < 2; ++rt)
#pragma unroll
    for (int kk = 0; kk < 2; ++kk)
      qf[rt][kk] = *(const bf16x8*)&qbase[(size_t)(rt * 16 + li) * 64 + kk * 32 + lg * 8];

  f32x4 sf[2][8];
#pragma unroll
  for (int rt = 0; rt < 2; ++rt)
#pragma unroll
    for (int jt = 0; jt < 8; ++jt) sf[rt][jt] = (f32x4){0.f, 0.f, 0.f, 0.f};

  const u16* abase = ab + h * 128 * 64;
#pragma unroll
  for (int jt = 0; jt < 8; ++jt)
#pragma unroll
    for (int kk = 0; kk < 2; ++kk) {
      bf16x8 bfr = *(const bf16x8*)&abase[(size_t)(jt * 16 + li) * 64 + kk * 32 + lg * 8];
      sf[0][jt] = MFMA16(qf[0][kk], bfr, sf[0][jt]);
      sf[1][jt] = MFMA16(qf[1][kk], bfr, sf[1][jt]);
    }
  float inv[2][4];
#pragma unroll
  for (int rt = 0; rt < 2; ++rt)
#pragma unroll
    for (int r = 0; r < 4; ++r) {
      float cm = sf[rt][0][r];
#pragma unroll
      for (int jt = 1; jt < 8; ++jt) cm = fmaxf(cm, sf[rt][jt][r]);
#pragma unroll
      for (int off = 1; off < 16; off <<= 1) cm = fmaxf(cm, __shfl_xor(cm, off));
      float ss = 0.f;
#pragma unroll
      for (int jt = 0; jt < 8; ++jt) {
        float p = __expf(sf[rt][jt][r] - cm);
        sf[rt][jt][r] = p;
        ss += p;
      }
#pragma unroll
      for (int off = 1; off < 16; off <<= 1) ss += __shfl_xor(ss, off);
      inv[rt][r] = 1.f / ss;
    }
#pragma unroll
  for (int rt = 0; rt < 2; ++rt)
#pragma unroll
    for (int jt = 0; jt < 8; ++jt)
#pragma unroll
      for (int r = 0; r < 4; ++r)
        p_lds[w * 32 + rt * 16 + lg * 4 + r][jt * 16 + li] = f2bf(sf[rt][jt][r]);

  f32x4 O[2][4];
#pragma unroll
  for (int rt = 0; rt < 2; ++rt)
#pragma unroll
    for (int dt = 0; dt < 4; ++dt) O[rt][dt] = (f32x4){0.f, 0.f, 0.f, 0.f};

  const u16* obase = out1t + (size_t)bh * 64 * 128;
#pragma unroll
  for (int ks = 0; ks < 4; ++ks) {
    bf16x8 pa0 = *(const bf16x8*)&p_lds[w * 32 + li][ks * 32 + lg * 8];
    bf16x8 pa1 = *(const bf16x8*)&p_lds[w * 32 + 16 + li][ks * 32 + lg * 8];
#pragma unroll
    for (int dt = 0; dt < 4; ++dt) {
      bf16x8 bv = *(const bf16x8*)&obase[(size_t)(dt * 16 + li) * 128 + ks * 32 + lg * 8];
      O[0][dt] = MFMA16(pa0, bv, O[0][dt]);
      O[1][dt] = MFMA16(pa1, bv, O[1][dt]);
    }
  }
#pragma unroll
  for (int rt = 0; rt < 2; ++rt)
#pragma unroll
    for (int dt = 0; dt < 4; ++dt)
#pragma unroll
      for (int r = 0; r < 4; ++r) {
        int nn = n0 + w * 32 + rt * 16 + lg * 4 + r;
        int col = h * 64 + dt * 16 + li;
        out2[((size_t)b * 4096 + nn) * 1024 + col] = f2bf(O[rt][dt][r] * inv[rt][r]);
      }
}

// ---------------- launch ----------------
extern "C" void kernel_launch(void* const* d_in, const int* in_sizes, int n_in,
                              void* d_out, int out_size, void* d_ws, size_t ws_size,
                              hipStream_t stream) {
  const float* x = (const float*)d_in[0];
  const float* Wqkv = (const float*)d_in[1];
  const float* agent = (const float*)d_in[2];
  const float* Wout = (const float*)d_in[3];
  float* out = (float*)d_out;

  char* ws = (char*)d_ws;
  u16* x_bf  = (u16*)(ws + 0);           // 32 MB; reused as out2
  u16* wqkvT = (u16*)(ws + 33554432);    // 6 MB
  u16* woutT = (u16*)(ws + 39845888);    // 2 MB
  u16* a_bf  = (u16*)(ws + 41943040);    // 256 KB
  u16* qb    = (u16*)(ws + 42205184);    // 32 MB
  u16* kb    = (u16*)(ws + 75759616);    // 32 MB
  float* pO  = (float*)(ws + 109314048); // 16 MB used (8-split partials)
  u16* vt    = (u16*)(ws + 142868480);   // 32 MB
  float* pM  = (float*)(ws + 176422912); // 512 KB
  float* pL  = (float*)(ws + 176947200); // 512 KB
  u16* out1t = (u16*)(ws + 177471488);   // 1 MB
  u16* out2  = x_bf;

  (void)hipFuncSetAttribute((const void*)gemm256<0>, hipFuncAttributeMaxDynamicSharedMemorySize, 131072);
  (void)hipFuncSetAttribute((const void*)gemm256<1>, hipFuncAttributeMaxDynamicSharedMemorySize, 131072);

  prep<<<9728, 256, 0, stream>>>(x, x_bf, Wqkv, wqkvT, Wout, woutT, agent, a_bf);
  gemm256<0><<<768, 512, 131072, stream>>>(x_bf, wqkvT, 16384, 3072, 1024, qb, kb, vt, nullptr);
  ak_flash<<<512, 256, 0, stream>>>(kb, vt, a_bf, pO, pM, pL);
  ak_combine<<<512, 128, 0, stream>>>(pO, pM, pL, out1t);
  qa_fused<<<2048, 256, 0, stream>>>(qb, out1t, a_bf, out2);
  gemm256<1><<<256, 512, 131072, stream>>>(out2, woutT, 16384, 1024, 1024, nullptr, nullptr, nullptr, out);
}

// Round 12
// 278.409 us; speedup vs baseline: 1.2499x; 1.2499x over previous
//
#include <hip/hip_runtime.h>

typedef __bf16 bf16x8 __attribute__((ext_vector_type(8)));
typedef float f32x4 __attribute__((ext_vector_type(4)));
typedef unsigned short ushort8 __attribute__((ext_vector_type(8)));
typedef unsigned short u16;

#define MFMA16(a, b, c) __builtin_amdgcn_mfma_f32_16x16x32_bf16(a, b, c, 0, 0, 0)
#define FENCE() __builtin_amdgcn_sched_barrier(0)
#define BARRIER() do { FENCE(); __builtin_amdgcn_s_barrier(); FENCE(); } while (0)
#define VMCNT(n) do { asm volatile("s_waitcnt vmcnt(" #n ")"); FENCE(); } while (0)

__device__ __forceinline__ u16 f2bf(float v) {
  unsigned int u = __builtin_bit_cast(unsigned int, v);
  u += 0x7fffu + ((u >> 16) & 1u);   // RNE; inputs are finite
  return (u16)(u >> 16);
}

__device__ __forceinline__ void gload16(const u16* g, u16* l) {
  __builtin_amdgcn_global_load_lds((__attribute__((address_space(1))) void*)(g),
                                   (__attribute__((address_space(3))) void*)(l), 16, 0, 0);
}

// ---------------- fused prep: x->bf16, Wqkv^T, Wout^T, agent*scale ----------------
__global__ __launch_bounds__(256) void prep(const float* __restrict__ x, u16* __restrict__ x_bf,
                                            const float* __restrict__ Wqkv, u16* __restrict__ wqkvT,
                                            const float* __restrict__ Wout, u16* __restrict__ woutT,
                                            const float* __restrict__ agent, u16* __restrict__ a_bf) {
  __shared__ float tile[64][65];
  int bid = blockIdx.x;
  int t = threadIdx.x;
  if (bid < 8192) {
    size_t i = (size_t)bid * 256 + t;
    const float4* p = (const float4*)x + i * 2;
    float4 a = p[0], b = p[1];
    ushort8 o;
    o[0] = f2bf(a.x); o[1] = f2bf(a.y); o[2] = f2bf(a.z); o[3] = f2bf(a.w);
    o[4] = f2bf(b.x); o[5] = f2bf(b.y); o[6] = f2bf(b.z); o[7] = f2bf(b.w);
    *((ushort8*)x_bf + i) = o;
    return;
  }
  if (bid >= 9216) {
    int i = (bid - 9216) * 256 + t;
    a_bf[i] = f2bf(agent[i] * 0.125f);
    return;
  }
  const float* W; u16* WT; int K = 1024, N; int b2;
  if (bid < 8960) { W = Wqkv; WT = wqkvT; N = 3072; b2 = bid - 8192; }
  else            { W = Wout; WT = woutT; N = 1024; b2 = bid - 8960; }
  int nt = N >> 6;
  int kt = b2 / nt, nti = b2 - kt * nt;
  int k0 = kt << 6, n0 = nti << 6;
  int r = t >> 4, c4 = (t & 15) << 2;
#pragma unroll
  for (int j = 0; j < 4; ++j) {
    float4 v = *(const float4*)&W[(size_t)(k0 + j * 16 + r) * N + n0 + c4];
    tile[j * 16 + r][c4] = v.x; tile[j * 16 + r][c4 + 1] = v.y;
    tile[j * 16 + r][c4 + 2] = v.z; tile[j * 16 + r][c4 + 3] = v.w;
  }
  __syncthreads();
  int rn = t >> 2, cs = (t & 3) << 4;
  ushort8 o0, o1;
#pragma unroll
  for (int e = 0; e < 8; ++e) { o0[e] = f2bf(tile[cs + e][rn]); o1[e] = f2bf(tile[cs + 8 + e][rn]); }
  u16* dst = WT + (size_t)(n0 + rn) * K + k0 + cs;
  *(ushort8*)dst = o0;
  *(ushort8*)(dst + 8) = o1;
}

// ---------------- 256^2 deep-pipelined GEMM (round-7 schedule, best measured) ----------------
// MODE 0: q,k -> (b,h,n,d) direct; v -> vt (b,h,d,n) via 128KB LDS bounce (coalesced).
// MODE 1: f32 row-major out.
template <int MODE>
__global__ __launch_bounds__(512, 2) void gemm256(const u16* __restrict__ A, const u16* __restrict__ BT,
                                                  int M, int N, int K,
                                                  u16* __restrict__ qb, u16* __restrict__ kb,
                                                  u16* __restrict__ vt, float* __restrict__ outf) {
  extern __shared__ char smem[];   // 131072 bytes
  const int NT = K >> 5;
  int ntiles = N >> 8;
  int nwg = (M >> 8) * ntiles;
  int bid = blockIdx.x;
  int wg = (bid & 7) * (nwg >> 3) + (bid >> 3);   // XCD swizzle; nwg % 8 == 0
  int tm = wg / ntiles, tn = wg - tm * ntiles;
  int rb = tm << 8, cb = tn << 8;
  int t = threadIdx.x;
  int w = t >> 6, lane = t & 63, li = lane & 15, lg = lane >> 4;
  int wr = w >> 2, wc = w & 3;

  const u16* srcA[2];
  const u16* srcB[2];
#pragma unroll
  for (int j = 0; j < 2; ++j) {
    int D = j * 8192 + t * 16;
    int L = D ^ (((D >> 7) & 3) << 4);
    int row = L >> 6, inb = L & 63;
    srcA[j] = A + (size_t)(rb + row) * K + (inb >> 1);
    srcB[j] = BT + (size_t)(cb + row) * K + (inb >> 1);
  }
#define STAGE_A(slot, kt) do { \
    gload16(srcA[0] + (kt) * 32, (u16*)(smem + (slot) * 32768 + t * 16)); \
    gload16(srcA[1] + (kt) * 32, (u16*)(smem + (slot) * 32768 + 8192 + t * 16)); } while (0)
#define STAGE_B(slot, kt) do { \
    gload16(srcB[0] + (kt) * 32, (u16*)(smem + (slot) * 32768 + 16384 + t * 16)); \
    gload16(srcB[1] + (kt) * 32, (u16*)(smem + (slot) * 32768 + 24576 + t * 16)); } while (0)

  int offA[8], offB[4];
#pragma unroll
  for (int m8 = 0; m8 < 8; ++m8) {
    int row = wr * 128 + m8 * 16 + li;
    int L = row * 64 + lg * 16;
    offA[m8] = L ^ (((L >> 7) & 3) << 4);
  }
#pragma unroll
  for (int n = 0; n < 4; ++n) {
    int row = wc * 64 + n * 16 + li;
    int L = row * 64 + lg * 16;
    offB[n] = 16384 + (L ^ (((L >> 7) & 3) << 4));
  }

  f32x4 acc[8][4];
#pragma unroll
  for (int m = 0; m < 8; ++m)
#pragma unroll
    for (int n = 0; n < 4; ++n) acc[m][n] = (f32x4){0.f, 0.f, 0.f, 0.f};

  bf16x8 aF[4], aS[4], b0[4], b1[4];

#define RD_A_LO(sb, d) do { d[0] = *(const bf16x8*)((sb) + offA[0]); d[1] = *(const bf16x8*)((sb) + offA[1]); \
                            d[2] = *(const bf16x8*)((sb) + offA[2]); d[3] = *(const bf16x8*)((sb) + offA[3]); } while (0)
#define RD_A_HI(sb, d) do { d[0] = *(const bf16x8*)((sb) + offA[4]); d[1] = *(const bf16x8*)((sb) + offA[5]); \
                            d[2] = *(const bf16x8*)((sb) + offA[6]); d[3] = *(const bf16x8*)((sb) + offA[7]); } while (0)
#define RD_B(sb, d)    do { d[0] = *(const bf16x8*)((sb) + offB[0]); d[1] = *(const bf16x8*)((sb) + offB[1]); \
                            d[2] = *(const bf16x8*)((sb) + offB[2]); d[3] = *(const bf16x8*)((sb) + offB[3]); } while (0)

#define PH_EVEN(t, BC, STG) do { \
    BARRIER(); \
    { char* sb_ = smem + ((t) & 3) * 32768; RD_A_HI(sb_, aS); } \
    if (STG) STAGE_A(((t) + 3) & 3, (t) + 3); \
    FENCE(); \
    __builtin_amdgcn_s_setprio(1); \
    _Pragma("unroll") for (int m = 0; m < 4; ++m) \
      _Pragma("unroll") for (int n = 0; n < 4; ++n) acc[m][n] = MFMA16(aF[m], BC[n], acc[m][n]); \
    __builtin_amdgcn_s_setprio(0); \
  } while (0)

#define PH_ODD(t, BC, BN, STG, RDNEXT, WAITOP) do { \
    WAITOP; \
    BARRIER(); \
    if (RDNEXT) { char* sb_ = smem + (((t) + 1) & 3) * 32768; RD_A_LO(sb_, aF); RD_B(sb_, BN); } \
    if (STG) STAGE_B(((t) + 3) & 3, (t) + 3); \
    FENCE(); \
    __builtin_amdgcn_s_setprio(1); \
    _Pragma("unroll") for (int m = 0; m < 4; ++m) \
      _Pragma("unroll") for (int n = 0; n < 4; ++n) acc[4 + m][n] = MFMA16(aS[m], BC[n], acc[4 + m][n]); \
    __builtin_amdgcn_s_setprio(0); \
  } while (0)

#define TILE(t, BC, BN, STG, RDNEXT, WAITOP) do { \
    PH_EVEN(t, BC, STG); \
    PH_ODD(t, BC, BN, STG, RDNEXT, WAITOP); \
  } while (0)

  STAGE_A(0, 0); STAGE_B(0, 0);
  STAGE_A(1, 1); STAGE_B(1, 1);
  STAGE_A(2, 2); STAGE_B(2, 2);
  VMCNT(8);
  BARRIER();
  RD_A_LO(smem, aF); RD_B(smem, b0);

  for (int tt = 0; tt <= NT - 6; tt += 2) {
    TILE(tt,     b0, b1, 1, 1, VMCNT(6));
    TILE(tt + 1, b1, b0, 1, 1, VMCNT(6));
  }
  TILE(NT - 4, b0, b1, 1, 1, VMCNT(6));
  TILE(NT - 3, b1, b0, 0, 1, VMCNT(4));
  TILE(NT - 2, b0, b1, 0, 1, VMCNT(0));
  TILE(NT - 1, b1, b0, 0, 0, ((void)0));

  if (MODE == 0) {
    int col0 = cb + wc * 64;
    int s = col0 >> 10;                 // block-uniform (cb 256-aligned)
    int hh = (col0 >> 6) & 15;
    if (s < 2) {
      u16* dst = (s == 0) ? qb : kb;
#pragma unroll
      for (int m = 0; m < 8; ++m) {
        int rbase = rb + wr * 128 + m * 16 + lg * 4;
#pragma unroll
        for (int r = 0; r < 4; ++r) {
          int rr = rbase + r;
          size_t o = (((size_t)(rr >> 12) * 16 + hh) * 4096 + (rr & 4095)) * 64;
#pragma unroll
          for (int n = 0; n < 4; ++n) dst[o + n * 16 + li] = f2bf(acc[m][n][r]);
        }
      }
    } else {
      // V tile 256x256 bf16 = 128KB: bounce through LDS (col-major, swizzled), store coalesced.
      BARRIER();   // K-loop LDS reads done everywhere before overwrite
#pragma unroll
      for (int m = 0; m < 8; ++m) {
        int rl = wr * 128 + m * 16 + lg * 4;
#pragma unroll
        for (int n = 0; n < 4; ++n) {
          int colL = wc * 64 + n * 16 + li;
          unsigned int lo = (unsigned int)f2bf(acc[m][n][0]) | ((unsigned int)f2bf(acc[m][n][1]) << 16);
          unsigned int hi = (unsigned int)f2bf(acc[m][n][2]) | ((unsigned int)f2bf(acc[m][n][3]) << 16);
          int byte = (colL * 512 + rl * 2) ^ ((colL & 7) << 4);
          *(uint2*)(smem + byte) = make_uint2(lo, hi);
        }
      }
      BARRIER();
      int bb = rb >> 12, nnb = rb & 4095;
      int hh0b = (cb >> 6) & 15;
#pragma unroll
      for (int it = 0; it < 16; ++it) {
        int c = (it & 3) * 64 + w * 8 + (lane >> 3);     // col 0..255
        int k = (it >> 2) * 8 + (lane & 7);              // 16B row-chunk 0..31
        int kk = (k & ~7) | ((k & 7) ^ (c & 7));         // un-swizzle chunk
        uint4 v = *(const uint4*)(smem + c * 512 + kk * 16);
        size_t off = (((size_t)bb * 16 + hh0b + (c >> 6)) * 64 + (c & 63)) * 4096 + nnb + k * 8;
        *(uint4*)(vt + off) = v;
      }
    }
  } else {
#pragma unroll
    for (int m = 0; m < 8; ++m) {
#pragma unroll
      for (int r = 0; r < 4; ++r) {
        float* po = outf + (size_t)(rb + wr * 128 + m * 16 + lg * 4 + r) * N + cb + wc * 64;
#pragma unroll
        for (int n = 0; n < 4; ++n) po[n * 16 + li] = acc[m][n][r];
      }
    }
  }
#undef TILE
#undef PH_ODD
#undef PH_EVEN
#undef RD_A_LO
#undef RD_A_HI
#undef RD_B
#undef STAGE_A
#undef STAGE_B
}

// ---------------- agent<-key flash attention (softmax over n), 8-way n-split ----------------
__global__ __launch_bounds__(256) void ak_flash(const u16* __restrict__ kb, const u16* __restrict__ vt,
                                                const u16* __restrict__ ab,
                                                float* __restrict__ pO, float* __restrict__ pM,
                                                float* __restrict__ pL) {
  __shared__ u16 p_lds[128][136];
  int bid = blockIdx.x;
  int s = bid & 7;
  int bh = bid >> 3;
  int h = bh & 15;
  int t = threadIdx.x, w = t >> 6, l = t & 63, lg = l >> 4, li = l & 15;
  int jb = w * 32;

  bf16x8 afr[2][2];
#pragma unroll
  for (int jt = 0; jt < 2; ++jt)
#pragma unroll
    for (int kk = 0; kk < 2; ++kk)
      afr[jt][kk] = *(const bf16x8*)&ab[(size_t)(h * 128 + jb + jt * 16 + li) * 64 + kk * 32 + lg * 8];

  f32x4 O[2][4];
  float mrow[2][4], lrow[2][4];
#pragma unroll
  for (int jt = 0; jt < 2; ++jt) {
#pragma unroll
    for (int dt = 0; dt < 4; ++dt) O[jt][dt] = (f32x4){0.f, 0.f, 0.f, 0.f};
#pragma unroll
    for (int r = 0; r < 4; ++r) { mrow[jt][r] = -1e30f; lrow[jt][r] = 0.f; }
  }
  const u16* kbase = kb + (size_t)bh * 4096 * 64;
  const u16* vbase = vt + (size_t)bh * 64 * 4096;

  for (int c = 0; c < 4; ++c) {
    int i0 = s * 512 + c * 128;
    f32x4 sf[2][8];
#pragma unroll
    for (int jt = 0; jt < 2; ++jt)
#pragma unroll
      for (int it = 0; it < 8; ++it) sf[jt][it] = (f32x4){0.f, 0.f, 0.f, 0.f};
#pragma unroll
    for (int it = 0; it < 8; ++it)
#pragma unroll
      for (int kk = 0; kk < 2; ++kk) {
        bf16x8 bfr = *(const bf16x8*)&kbase[(size_t)(i0 + it * 16 + li) * 64 + kk * 32 + lg * 8];
        sf[0][it] = MFMA16(afr[0][kk], bfr, sf[0][it]);
        sf[1][it] = MFMA16(afr[1][kk], bfr, sf[1][it]);
      }
#pragma unroll
    for (int jt = 0; jt < 2; ++jt)
#pragma unroll
      for (int r = 0; r < 4; ++r) {
        float cm = sf[jt][0][r];
#pragma unroll
        for (int it = 1; it < 8; ++it) cm = fmaxf(cm, sf[jt][it][r]);
#pragma unroll
        for (int off = 1; off < 16; off <<= 1) cm = fmaxf(cm, __shfl_xor(cm, off));
        float mold = mrow[jt][r];
        float mnew = fmaxf(mold, cm);
        float scale = __expf(mold - mnew);
        float ss = 0.f;
#pragma unroll
        for (int it = 0; it < 8; ++it) {
          float p = __expf(sf[jt][it][r] - mnew);
          sf[jt][it][r] = p;
          ss += p;
        }
#pragma unroll
        for (int off = 1; off < 16; off <<= 1) ss += __shfl_xor(ss, off);
        lrow[jt][r] = lrow[jt][r] * scale + ss;
        mrow[jt][r] = mnew;
#pragma unroll
        for (int dt = 0; dt < 4; ++dt) O[jt][dt][r] *= scale;
      }
#pragma unroll
    for (int jt = 0; jt < 2; ++jt)
#pragma unroll
      for (int it = 0; it < 8; ++it)
#pragma unroll
        for (int r = 0; r < 4; ++r)
          p_lds[jb + jt * 16 + lg * 4 + r][it * 16 + li] = f2bf(sf[jt][it][r]);
#pragma unroll
    for (int ks = 0; ks < 4; ++ks) {
      bf16x8 pa0 = *(const bf16x8*)&p_lds[jb + li][ks * 32 + lg * 8];
      bf16x8 pa1 = *(const bf16x8*)&p_lds[jb + 16 + li][ks * 32 + lg * 8];
#pragma unroll
      for (int dt = 0; dt < 4; ++dt) {
        bf16x8 bv = *(const bf16x8*)&vbase[(size_t)(dt * 16 + li) * 4096 + i0 + ks * 32 + lg * 8];
        O[0][dt] = MFMA16(pa0, bv, O[0][dt]);
        O[1][dt] = MFMA16(pa1, bv, O[1][dt]);
      }
    }
  }
  size_t pb = ((size_t)bh * 8 + s) * 128;
#pragma unroll
  for (int jt = 0; jt < 2; ++jt)
#pragma unroll
    for (int dt = 0; dt < 4; ++dt)
#pragma unroll
      for (int r = 0; r < 4; ++r) {
        int j = jb + jt * 16 + lg * 4 + r;
        pO[(pb + j) * 64 + dt * 16 + li] = O[jt][dt][r];
      }
  if (li == 0) {
#pragma unroll
    for (int jt = 0; jt < 2; ++jt)
#pragma unroll
      for (int r = 0; r < 4; ++r) {
        int j = jb + jt * 16 + lg * 4 + r;
        pM[pb + j] = mrow[jt][r];
        pL[pb + j] = lrow[jt][r];
      }
  }
}

// combine split partials -> out1t (bh, d, j). grid 64*8 (bh x d-chunk), 128 thr (j).
__global__ __launch_bounds__(128) void ak_combine(const float* __restrict__ pO, const float* __restrict__ pM,
                                                  const float* __restrict__ pL, u16* __restrict__ out1t) {
  int bh = blockIdx.x >> 3, dc = blockIdx.x & 7;
  int j = threadIdx.x;
  float ms[8], wv[8];
  float M = -1e30f;
#pragma unroll
  for (int s = 0; s < 8; ++s) { ms[s] = pM[((size_t)bh * 8 + s) * 128 + j]; M = fmaxf(M, ms[s]); }
  float L = 0.f;
#pragma unroll
  for (int s = 0; s < 8; ++s) { wv[s] = __expf(ms[s] - M); L += wv[s] * pL[((size_t)bh * 8 + s) * 128 + j]; }
  float inv = 1.f / L;
  float4 A = {0.f, 0.f, 0.f, 0.f}, B = {0.f, 0.f, 0.f, 0.f};
#pragma unroll
  for (int s = 0; s < 8; ++s) {
    const float4* p = (const float4*)&pO[(((size_t)bh * 8 + s) * 128 + j) * 64 + dc * 8];
    float4 x = p[0], y = p[1];
    A.x += wv[s] * x.x; A.y += wv[s] * x.y; A.z += wv[s] * x.z; A.w += wv[s] * x.w;
    B.x += wv[s] * y.x; B.y += wv[s] * y.y; B.z += wv[s] * y.z; B.w += wv[s] * y.w;
  }
  size_t ob = ((size_t)bh * 64 + dc * 8) * 128 + j;
  out1t[ob + 0 * 128] = f2bf(A.x * inv);
  out1t[ob + 1 * 128] = f2bf(A.y * inv);
  out1t[ob + 2 * 128] = f2bf(A.z * inv);
  out1t[ob + 3 * 128] = f2bf(A.w * inv);
  out1t[ob + 4 * 128] = f2bf(B.x * inv);
  out1t[ob + 5 * 128] = f2bf(B.y * inv);
  out1t[ob + 6 * 128] = f2bf(B.z * inv);
  out1t[ob + 7 * 128] = f2bf(B.w * inv);
}

// ---------------- q<-agent attention fused with P@out1 ----------------
__global__ __launch_bounds__(256) void qa_fused(const u16* __restrict__ qb, const u16* __restrict__ out1t,
                                                const u16* __restrict__ ab, u16* __restrict__ out2) {
  __shared__ u16 p_lds[128][136];
  int bid = blockIdx.x;
  int nt = bid & 31;
  int bh = bid >> 5;
  int h = bh & 15, b = bh >> 4;
  int t = threadIdx.x, w = t >> 6, l = t & 63, lg = l >> 4, li = l & 15;
  int n0 = nt * 128;

  const u16* qbase = qb + ((size_t)bh * 4096 + n0 + w * 32) * 64;
  bf16x8 qf[2][2];
#pragma unroll
  for (int rt = 0; rt < 2; ++rt)
#pragma unroll
    for (int kk = 0; kk < 2; ++kk)
      qf[rt][kk] = *(const bf16x8*)&qbase[(size_t)(rt * 16 + li) * 64 + kk * 32 + lg * 8];

  f32x4 sf[2][8];
#pragma unroll
  for (int rt = 0; rt < 2; ++rt)
#pragma unroll
    for (int jt = 0; jt < 8; ++jt) sf[rt][jt] = (f32x4){0.f, 0.f, 0.f, 0.f};

  const u16* abase = ab + h * 128 * 64;
#pragma unroll
  for (int jt = 0; jt < 8; ++jt)
#pragma unroll
    for (int kk = 0; kk < 2; ++kk) {
      bf16x8 bfr = *(const bf16x8*)&abase[(size_t)(jt * 16 + li) * 64 + kk * 32 + lg * 8];
      sf[0][jt] = MFMA16(qf[0][kk], bfr, sf[0][jt]);
      sf[1][jt] = MFMA16(qf[1][kk], bfr, sf[1][jt]);
    }
  float inv[2][4];
#pragma unroll
  for (int rt = 0; rt < 2; ++rt)
#pragma unroll
    for (int r = 0; r < 4; ++r) {
      float cm = sf[rt][0][r];
#pragma unroll
      for (int jt = 1; jt < 8; ++jt) cm = fmaxf(cm, sf[rt][jt][r]);
#pragma unroll
      for (int off = 1; off < 16; off <<= 1) cm = fmaxf(cm, __shfl_xor(cm, off));
      float ss = 0.f;
#pragma unroll
      for (int jt = 0; jt < 8; ++jt) {
        float p = __expf(sf[rt][jt][r] - cm);
        sf[rt][jt][r] = p;
        ss += p;
      }
#pragma unroll
      for (int off = 1; off < 16; off <<= 1) ss += __shfl_xor(ss, off);
      inv[rt][r] = 1.f / ss;
    }
#pragma unroll
  for (int rt = 0; rt < 2; ++rt)
#pragma unroll
    for (int jt = 0; jt < 8; ++jt)
#pragma unroll
      for (int r = 0; r < 4; ++r)
        p_lds[w * 32 + rt * 16 + lg * 4 + r][jt * 16 + li] = f2bf(sf[rt][jt][r]);

  f32x4 O[2][4];
#pragma unroll
  for (int rt = 0; rt < 2; ++rt)
#pragma unroll
    for (int dt = 0; dt < 4; ++dt) O[rt][dt] = (f32x4){0.f, 0.f, 0.f, 0.f};

  const u16* obase = out1t + (size_t)bh * 64 * 128;
#pragma unroll
  for (int ks = 0; ks < 4; ++ks) {
    bf16x8 pa0 = *(const bf16x8*)&p_lds[w * 32 + li][ks * 32 + lg * 8];
    bf16x8 pa1 = *(const bf16x8*)&p_lds[w * 32 + 16 + li][ks * 32 + lg * 8];
#pragma unroll
    for (int dt = 0; dt < 4; ++dt) {
      bf16x8 bv = *(const bf16x8*)&obase[(size_t)(dt * 16 + li) * 128 + ks * 32 + lg * 8];
      O[0][dt] = MFMA16(pa0, bv, O[0][dt]);
      O[1][dt] = MFMA16(pa1, bv, O[1][dt]);
    }
  }
#pragma unroll
  for (int rt = 0; rt < 2; ++rt)
#pragma unroll
    for (int dt = 0; dt < 4; ++dt)
#pragma unroll
      for (int r = 0; r < 4; ++r) {
        int nn = n0 + w * 32 + rt * 16 + lg * 4 + r;
        int col = h * 64 + dt * 16 + li;
        out2[((size_t)b * 4096 + nn) * 1024 + col] = f2bf(O[rt][dt][r] * inv[rt][r]);
      }
}

// ---------------- launch ----------------
extern "C" void kernel_launch(void* const* d_in, const int* in_sizes, int n_in,
                              void* d_out, int out_size, void* d_ws, size_t ws_size,
                              hipStream_t stream) {
  const float* x = (const float*)d_in[0];
  const float* Wqkv = (const float*)d_in[1];
  const float* agent = (const float*)d_in[2];
  const float* Wout = (const float*)d_in[3];
  float* out = (float*)d_out;

  char* ws = (char*)d_ws;
  u16* x_bf  = (u16*)(ws + 0);
  u16* wqkvT = (u16*)(ws + 33554432);
  u16* woutT = (u16*)(ws + 39845888);
  u16* a_bf  = (u16*)(ws + 41943040);
  u16* qb    = (u16*)(ws + 42205184);
  u16* kb    = (u16*)(ws + 75759616);
  u16* vt    = (u16*)(ws + 142868480);
  float* pO  = (float*)(ws + 176422912);
  float* pM  = (float*)(ws + 193200128);
  float* pL  = (float*)(ws + 193724416);
  u16* out1t = (u16*)(ws + 194248704);
  u16* out2  = x_bf;

  (void)hipFuncSetAttribute((const void*)gemm256<0>, hipFuncAttributeMaxDynamicSharedMemorySize, 131072);
  (void)hipFuncSetAttribute((const void*)gemm256<1>, hipFuncAttributeMaxDynamicSharedMemorySize, 131072);

  prep<<<9728, 256, 0, stream>>>(x, x_bf, Wqkv, wqkvT, Wout, woutT, agent, a_bf);
  gemm256<0><<<768, 512, 131072, stream>>>(x_bf, wqkvT, 16384, 3072, 1024, qb, kb, vt, nullptr);
  ak_flash<<<512, 256, 0, stream>>>(kb, vt, a_bf, pO, pM, pL);
  ak_combine<<<512, 128, 0, stream>>>(pO, pM, pL, out1t);
  qa_fused<<<2048, 256, 0, stream>>>(qb, out1t, a_bf, out2);
  gemm256<1><<<256, 512, 131072, stream>>>(out2, woutT, 16384, 1024, 1024, nullptr, nullptr, nullptr, out);
}

// Round 13
// 276.121 us; speedup vs baseline: 1.2603x; 1.0083x over previous
//
#include <hip/hip_runtime.h>

typedef __bf16 bf16x8 __attribute__((ext_vector_type(8)));
typedef float f32x4 __attribute__((ext_vector_type(4)));
typedef unsigned short ushort8 __attribute__((ext_vector_type(8)));
typedef unsigned short u16;

#define MFMA16(a, b, c) __builtin_amdgcn_mfma_f32_16x16x32_bf16(a, b, c, 0, 0, 0)
#define FENCE() __builtin_amdgcn_sched_barrier(0)
#define BARRIER() do { FENCE(); __builtin_amdgcn_s_barrier(); FENCE(); } while (0)
#define VMCNT(n) do { asm volatile("s_waitcnt vmcnt(" #n ")"); FENCE(); } while (0)

__device__ __forceinline__ u16 f2bf(float v) {
  unsigned int u = __builtin_bit_cast(unsigned int, v);
  u += 0x7fffu + ((u >> 16) & 1u);   // RNE; inputs are finite
  return (u16)(u >> 16);
}

__device__ __forceinline__ void gload16(const u16* g, u16* l) {
  __builtin_amdgcn_global_load_lds((__attribute__((address_space(1))) void*)(g),
                                   (__attribute__((address_space(3))) void*)(l), 16, 0, 0);
}

// ---------------- fused prep: x->bf16, Wqkv^T, Wout^T, agent*scale*log2e ----------------
// Logits are pre-scaled by log2(e); all softmax exponentials downstream use exp2f.
__global__ __launch_bounds__(256) void prep(const float* __restrict__ x, u16* __restrict__ x_bf,
                                            const float* __restrict__ Wqkv, u16* __restrict__ wqkvT,
                                            const float* __restrict__ Wout, u16* __restrict__ woutT,
                                            const float* __restrict__ agent, u16* __restrict__ a_bf) {
  __shared__ float tile[64][65];
  int bid = blockIdx.x;
  int t = threadIdx.x;
  if (bid < 8192) {
    size_t i = (size_t)bid * 256 + t;
    const float4* p = (const float4*)x + i * 2;
    float4 a = p[0], b = p[1];
    ushort8 o;
    o[0] = f2bf(a.x); o[1] = f2bf(a.y); o[2] = f2bf(a.z); o[3] = f2bf(a.w);
    o[4] = f2bf(b.x); o[5] = f2bf(b.y); o[6] = f2bf(b.z); o[7] = f2bf(b.w);
    *((ushort8*)x_bf + i) = o;
    return;
  }
  if (bid >= 9216) {
    int i = (bid - 9216) * 256 + t;
    a_bf[i] = f2bf(agent[i] * 0.1803368801f);   // 0.125 * log2(e)
    return;
  }
  const float* W; u16* WT; int K = 1024, N; int b2;
  if (bid < 8960) { W = Wqkv; WT = wqkvT; N = 3072; b2 = bid - 8192; }
  else            { W = Wout; WT = woutT; N = 1024; b2 = bid - 8960; }
  int nt = N >> 6;
  int kt = b2 / nt, nti = b2 - kt * nt;
  int k0 = kt << 6, n0 = nti << 6;
  int r = t >> 4, c4 = (t & 15) << 2;
#pragma unroll
  for (int j = 0; j < 4; ++j) {
    float4 v = *(const float4*)&W[(size_t)(k0 + j * 16 + r) * N + n0 + c4];
    tile[j * 16 + r][c4] = v.x; tile[j * 16 + r][c4 + 1] = v.y;
    tile[j * 16 + r][c4 + 2] = v.z; tile[j * 16 + r][c4 + 3] = v.w;
  }
  __syncthreads();
  int rn = t >> 2, cs = (t & 3) << 4;
  ushort8 o0, o1;
#pragma unroll
  for (int e = 0; e < 8; ++e) { o0[e] = f2bf(tile[cs + e][rn]); o1[e] = f2bf(tile[cs + 8 + e][rn]); }
  u16* dst = WT + (size_t)(n0 + rn) * K + k0 + cs;
  *(ushort8*)dst = o0;
  *(ushort8*)(dst + 8) = o1;
}

// ---------------- 256^2 deep-pipelined GEMM (round-7 schedule, best measured) ----------------
// MODE 0: q,k -> (b,h,n,d) direct; v -> vt (b,h,d,n) via 128KB LDS bounce (coalesced).
// MODE 1: f32 row-major out.
template <int MODE>
__global__ __launch_bounds__(512, 2) void gemm256(const u16* __restrict__ A, const u16* __restrict__ BT,
                                                  int M, int N, int K,
                                                  u16* __restrict__ qb, u16* __restrict__ kb,
                                                  u16* __restrict__ vt, float* __restrict__ outf) {
  extern __shared__ char smem[];   // 131072 bytes
  const int NT = K >> 5;
  int ntiles = N >> 8;
  int nwg = (M >> 8) * ntiles;
  int bid = blockIdx.x;
  int wg = (bid & 7) * (nwg >> 3) + (bid >> 3);   // XCD swizzle; nwg % 8 == 0
  int tm = wg / ntiles, tn = wg - tm * ntiles;
  int rb = tm << 8, cb = tn << 8;
  int t = threadIdx.x;
  int w = t >> 6, lane = t & 63, li = lane & 15, lg = lane >> 4;
  int wr = w >> 2, wc = w & 3;

  const u16* srcA[2];
  const u16* srcB[2];
#pragma unroll
  for (int j = 0; j < 2; ++j) {
    int D = j * 8192 + t * 16;
    int L = D ^ (((D >> 7) & 3) << 4);
    int row = L >> 6, inb = L & 63;
    srcA[j] = A + (size_t)(rb + row) * K + (inb >> 1);
    srcB[j] = BT + (size_t)(cb + row) * K + (inb >> 1);
  }
#define STAGE_A(slot, kt) do { \
    gload16(srcA[0] + (kt) * 32, (u16*)(smem + (slot) * 32768 + t * 16)); \
    gload16(srcA[1] + (kt) * 32, (u16*)(smem + (slot) * 32768 + 8192 + t * 16)); } while (0)
#define STAGE_B(slot, kt) do { \
    gload16(srcB[0] + (kt) * 32, (u16*)(smem + (slot) * 32768 + 16384 + t * 16)); \
    gload16(srcB[1] + (kt) * 32, (u16*)(smem + (slot) * 32768 + 24576 + t * 16)); } while (0)

  int offA[8], offB[4];
#pragma unroll
  for (int m8 = 0; m8 < 8; ++m8) {
    int row = wr * 128 + m8 * 16 + li;
    int L = row * 64 + lg * 16;
    offA[m8] = L ^ (((L >> 7) & 3) << 4);
  }
#pragma unroll
  for (int n = 0; n < 4; ++n) {
    int row = wc * 64 + n * 16 + li;
    int L = row * 64 + lg * 16;
    offB[n] = 16384 + (L ^ (((L >> 7) & 3) << 4));
  }

  f32x4 acc[8][4];
#pragma unroll
  for (int m = 0; m < 8; ++m)
#pragma unroll
    for (int n = 0; n < 4; ++n) acc[m][n] = (f32x4){0.f, 0.f, 0.f, 0.f};

  bf16x8 aF[4], aS[4], b0[4], b1[4];

#define RD_A_LO(sb, d) do { d[0] = *(const bf16x8*)((sb) + offA[0]); d[1] = *(const bf16x8*)((sb) + offA[1]); \
                            d[2] = *(const bf16x8*)((sb) + offA[2]); d[3] = *(const bf16x8*)((sb) + offA[3]); } while (0)
#define RD_A_HI(sb, d) do { d[0] = *(const bf16x8*)((sb) + offA[4]); d[1] = *(const bf16x8*)((sb) + offA[5]); \
                            d[2] = *(const bf16x8*)((sb) + offA[6]); d[3] = *(const bf16x8*)((sb) + offA[7]); } while (0)
#define RD_B(sb, d)    do { d[0] = *(const bf16x8*)((sb) + offB[0]); d[1] = *(const bf16x8*)((sb) + offB[1]); \
                            d[2] = *(const bf16x8*)((sb) + offB[2]); d[3] = *(const bf16x8*)((sb) + offB[3]); } while (0)

#define PH_EVEN(t, BC, STG) do { \
    BARRIER(); \
    { char* sb_ = smem + ((t) & 3) * 32768; RD_A_HI(sb_, aS); } \
    if (STG) STAGE_A(((t) + 3) & 3, (t) + 3); \
    FENCE(); \
    __builtin_amdgcn_s_setprio(1); \
    _Pragma("unroll") for (int m = 0; m < 4; ++m) \
      _Pragma("unroll") for (int n = 0; n < 4; ++n) acc[m][n] = MFMA16(aF[m], BC[n], acc[m][n]); \
    __builtin_amdgcn_s_setprio(0); \
  } while (0)

#define PH_ODD(t, BC, BN, STG, RDNEXT, WAITOP) do { \
    WAITOP; \
    BARRIER(); \
    if (RDNEXT) { char* sb_ = smem + (((t) + 1) & 3) * 32768; RD_A_LO(sb_, aF); RD_B(sb_, BN); } \
    if (STG) STAGE_B(((t) + 3) & 3, (t) + 3); \
    FENCE(); \
    __builtin_amdgcn_s_setprio(1); \
    _Pragma("unroll") for (int m = 0; m < 4; ++m) \
      _Pragma("unroll") for (int n = 0; n < 4; ++n) acc[4 + m][n] = MFMA16(aS[m], BC[n], acc[4 + m][n]); \
    __builtin_amdgcn_s_setprio(0); \
  } while (0)

#define TILE(t, BC, BN, STG, RDNEXT, WAITOP) do { \
    PH_EVEN(t, BC, STG); \
    PH_ODD(t, BC, BN, STG, RDNEXT, WAITOP); \
  } while (0)

  STAGE_A(0, 0); STAGE_B(0, 0);
  STAGE_A(1, 1); STAGE_B(1, 1);
  STAGE_A(2, 2); STAGE_B(2, 2);
  VMCNT(8);
  BARRIER();
  RD_A_LO(smem, aF); RD_B(smem, b0);

  for (int tt = 0; tt <= NT - 6; tt += 2) {
    TILE(tt,     b0, b1, 1, 1, VMCNT(6));
    TILE(tt + 1, b1, b0, 1, 1, VMCNT(6));
  }
  TILE(NT - 4, b0, b1, 1, 1, VMCNT(6));
  TILE(NT - 3, b1, b0, 0, 1, VMCNT(4));
  TILE(NT - 2, b0, b1, 0, 1, VMCNT(0));
  TILE(NT - 1, b1, b0, 0, 0, ((void)0));

  if (MODE == 0) {
    int col0 = cb + wc * 64;
    int s = col0 >> 10;                 // block-uniform (cb 256-aligned)
    int hh = (col0 >> 6) & 15;
    if (s < 2) {
      u16* dst = (s == 0) ? qb : kb;
#pragma unroll
      for (int m = 0; m < 8; ++m) {
        int rbase = rb + wr * 128 + m * 16 + lg * 4;
#pragma unroll
        for (int r = 0; r < 4; ++r) {
          int rr = rbase + r;
          size_t o = (((size_t)(rr >> 12) * 16 + hh) * 4096 + (rr & 4095)) * 64;
#pragma unroll
          for (int n = 0; n < 4; ++n) dst[o + n * 16 + li] = f2bf(acc[m][n][r]);
        }
      }
    } else {
      // V tile 256x256 bf16 = 128KB: bounce through LDS (col-major, swizzled), store coalesced.
      BARRIER();   // K-loop LDS reads done everywhere before overwrite
#pragma unroll
      for (int m = 0; m < 8; ++m) {
        int rl = wr * 128 + m * 16 + lg * 4;
#pragma unroll
        for (int n = 0; n < 4; ++n) {
          int colL = wc * 64 + n * 16 + li;
          unsigned int lo = (unsigned int)f2bf(acc[m][n][0]) | ((unsigned int)f2bf(acc[m][n][1]) << 16);
          unsigned int hi = (unsigned int)f2bf(acc[m][n][2]) | ((unsigned int)f2bf(acc[m][n][3]) << 16);
          int byte = (colL * 512 + rl * 2) ^ ((colL & 7) << 4);
          *(uint2*)(smem + byte) = make_uint2(lo, hi);
        }
      }
      BARRIER();
      int bb = rb >> 12, nnb = rb & 4095;
      int hh0b = (cb >> 6) & 15;
#pragma unroll
      for (int it = 0; it < 16; ++it) {
        int c = (it & 3) * 64 + w * 8 + (lane >> 3);     // col 0..255
        int k = (it >> 2) * 8 + (lane & 7);              // 16B row-chunk 0..31
        int kk = (k & ~7) | ((k & 7) ^ (c & 7));         // un-swizzle chunk
        uint4 v = *(const uint4*)(smem + c * 512 + kk * 16);
        size_t off = (((size_t)bb * 16 + hh0b + (c >> 6)) * 64 + (c & 63)) * 4096 + nnb + k * 8;
        *(uint4*)(vt + off) = v;
      }
    }
  } else {
#pragma unroll
    for (int m = 0; m < 8; ++m) {
#pragma unroll
      for (int r = 0; r < 4; ++r) {
        float* po = outf + (size_t)(rb + wr * 128 + m * 16 + lg * 4 + r) * N + cb + wc * 64;
#pragma unroll
        for (int n = 0; n < 4; ++n) po[n * 16 + li] = acc[m][n][r];
      }
    }
  }
#undef TILE
#undef PH_ODD
#undef PH_EVEN
#undef RD_A_LO
#undef RD_A_HI
#undef RD_B
#undef STAGE_A
#undef STAGE_B
}

// ---------------- agent<-key flash attention (softmax over n, base-2 logits), 8-way n-split ----------------
__global__ __launch_bounds__(256) void ak_flash(const u16* __restrict__ kb, const u16* __restrict__ vt,
                                                const u16* __restrict__ ab,
                                                float* __restrict__ pO, float* __restrict__ pM,
                                                float* __restrict__ pL) {
  __shared__ u16 p_lds[128][136];
  int bid = blockIdx.x;
  int s = bid & 7;
  int bh = bid >> 3;
  int h = bh & 15;
  int t = threadIdx.x, w = t >> 6, l = t & 63, lg = l >> 4, li = l & 15;
  int jb = w * 32;

  bf16x8 afr[2][2];
#pragma unroll
  for (int jt = 0; jt < 2; ++jt)
#pragma unroll
    for (int kk = 0; kk < 2; ++kk)
      afr[jt][kk] = *(const bf16x8*)&ab[(size_t)(h * 128 + jb + jt * 16 + li) * 64 + kk * 32 + lg * 8];

  f32x4 O[2][4];
  float mrow[2][4], lrow[2][4];
#pragma unroll
  for (int jt = 0; jt < 2; ++jt) {
#pragma unroll
    for (int dt = 0; dt < 4; ++dt) O[jt][dt] = (f32x4){0.f, 0.f, 0.f, 0.f};
#pragma unroll
    for (int r = 0; r < 4; ++r) { mrow[jt][r] = -1e30f; lrow[jt][r] = 0.f; }
  }
  const u16* kbase = kb + (size_t)bh * 4096 * 64;
  const u16* vbase = vt + (size_t)bh * 64 * 4096;

  for (int c = 0; c < 4; ++c) {
    int i0 = s * 512 + c * 128;
    f32x4 sf[2][8];
#pragma unroll
    for (int jt = 0; jt < 2; ++jt)
#pragma unroll
      for (int it = 0; it < 8; ++it) sf[jt][it] = (f32x4){0.f, 0.f, 0.f, 0.f};
#pragma unroll
    for (int it = 0; it < 8; ++it)
#pragma unroll
      for (int kk = 0; kk < 2; ++kk) {
        bf16x8 bfr = *(const bf16x8*)&kbase[(size_t)(i0 + it * 16 + li) * 64 + kk * 32 + lg * 8];
        sf[0][it] = MFMA16(afr[0][kk], bfr, sf[0][it]);
        sf[1][it] = MFMA16(afr[1][kk], bfr, sf[1][it]);
      }
#pragma unroll
    for (int jt = 0; jt < 2; ++jt)
#pragma unroll
      for (int r = 0; r < 4; ++r) {
        float cm = sf[jt][0][r];
#pragma unroll
        for (int it = 1; it < 8; ++it) cm = fmaxf(cm, sf[jt][it][r]);
#pragma unroll
        for (int off = 1; off < 16; off <<= 1) cm = fmaxf(cm, __shfl_xor(cm, off));
        float mold = mrow[jt][r];
        float mnew = fmaxf(mold, cm);
        float scale = exp2f(mold - mnew);
        float ss = 0.f;
#pragma unroll
        for (int it = 0; it < 8; ++it) {
          float p = exp2f(sf[jt][it][r] - mnew);
          sf[jt][it][r] = p;
          ss += p;
        }
#pragma unroll
        for (int off = 1; off < 16; off <<= 1) ss += __shfl_xor(ss, off);
        lrow[jt][r] = lrow[jt][r] * scale + ss;
        mrow[jt][r] = mnew;
#pragma unroll
        for (int dt = 0; dt < 4; ++dt) O[jt][dt][r] *= scale;
      }
#pragma unroll
    for (int jt = 0; jt < 2; ++jt)
#pragma unroll
      for (int it = 0; it < 8; ++it)
#pragma unroll
        for (int r = 0; r < 4; ++r)
          p_lds[jb + jt * 16 + lg * 4 + r][it * 16 + li] = f2bf(sf[jt][it][r]);
#pragma unroll
    for (int ks = 0; ks < 4; ++ks) {
      bf16x8 pa0 = *(const bf16x8*)&p_lds[jb + li][ks * 32 + lg * 8];
      bf16x8 pa1 = *(const bf16x8*)&p_lds[jb + 16 + li][ks * 32 + lg * 8];
#pragma unroll
      for (int dt = 0; dt < 4; ++dt) {
        bf16x8 bv = *(const bf16x8*)&vbase[(size_t)(dt * 16 + li) * 4096 + i0 + ks * 32 + lg * 8];
        O[0][dt] = MFMA16(pa0, bv, O[0][dt]);
        O[1][dt] = MFMA16(pa1, bv, O[1][dt]);
      }
    }
  }
  size_t pb = ((size_t)bh * 8 + s) * 128;
#pragma unroll
  for (int jt = 0; jt < 2; ++jt)
#pragma unroll
    for (int dt = 0; dt < 4; ++dt)
#pragma unroll
      for (int r = 0; r < 4; ++r) {
        int j = jb + jt * 16 + lg * 4 + r;
        pO[(pb + j) * 64 + dt * 16 + li] = O[jt][dt][r];
      }
  if (li == 0) {
#pragma unroll
    for (int jt = 0; jt < 2; ++jt)
#pragma unroll
      for (int r = 0; r < 4; ++r) {
        int j = jb + jt * 16 + lg * 4 + r;
        pM[pb + j] = mrow[jt][r];
        pL[pb + j] = lrow[jt][r];
      }
  }
}

// combine split partials (base-2 domain) -> out1t (bh, d, j). grid 64*8, 128 thr (j).
__global__ __launch_bounds__(128) void ak_combine(const float* __restrict__ pO, const float* __restrict__ pM,
                                                  const float* __restrict__ pL, u16* __restrict__ out1t) {
  int bh = blockIdx.x >> 3, dc = blockIdx.x & 7;
  int j = threadIdx.x;
  float ms[8], wv[8];
  float M = -1e30f;
#pragma unroll
  for (int s = 0; s < 8; ++s) { ms[s] = pM[((size_t)bh * 8 + s) * 128 + j]; M = fmaxf(M, ms[s]); }
  float L = 0.f;
#pragma unroll
  for (int s = 0; s < 8; ++s) { wv[s] = exp2f(ms[s] - M); L += wv[s] * pL[((size_t)bh * 8 + s) * 128 + j]; }
  float inv = 1.f / L;
  float4 A = {0.f, 0.f, 0.f, 0.f}, B = {0.f, 0.f, 0.f, 0.f};
#pragma unroll
  for (int s = 0; s < 8; ++s) {
    const float4* p = (const float4*)&pO[(((size_t)bh * 8 + s) * 128 + j) * 64 + dc * 8];
    float4 x = p[0], y = p[1];
    A.x += wv[s] * x.x; A.y += wv[s] * x.y; A.z += wv[s] * x.z; A.w += wv[s] * x.w;
    B.x += wv[s] * y.x; B.y += wv[s] * y.y; B.z += wv[s] * y.z; B.w += wv[s] * y.w;
  }
  size_t ob = ((size_t)bh * 64 + dc * 8) * 128 + j;
  out1t[ob + 0 * 128] = f2bf(A.x * inv);
  out1t[ob + 1 * 128] = f2bf(A.y * inv);
  out1t[ob + 2 * 128] = f2bf(A.z * inv);
  out1t[ob + 3 * 128] = f2bf(A.w * inv);
  out1t[ob + 4 * 128] = f2bf(B.x * inv);
  out1t[ob + 5 * 128] = f2bf(B.y * inv);
  out1t[ob + 6 * 128] = f2bf(B.z * inv);
  out1t[ob + 7 * 128] = f2bf(B.w * inv);
}

// ---------------- q<-agent attention (base-2 logits) fused with P@out1 ----------------
__global__ __launch_bounds__(256) void qa_fused(const u16* __restrict__ qb, const u16* __restrict__ out1t,
                                                const u16* __restrict__ ab, u16* __restrict__ out2) {
  __shared__ u16 p_lds[128][136];
  int bid = blockIdx.x;
  int nt = bid & 31;
  int bh = bid >> 5;
  int h = bh & 15, b = bh >> 4;
  int t = threadIdx.x, w = t >> 6, l = t & 63, lg = l >> 4, li = l & 15;
  int n0 = nt * 128;

  const u16* qbase = qb + ((size_t)bh * 4096 + n0 + w * 32) * 64;
  bf16x8 qf[2][2];
#pragma unroll
  for (int rt = 0; rt < 2; ++rt)
#pragma unroll
    for (int kk = 0; kk < 2; ++kk)
      qf[rt][kk] = *(const bf16x8*)&qbase[(size_t)(rt * 16 + li) * 64 + kk * 32 + lg * 8];

  f32x4 sf[2][8];
#pragma unroll
  for (int rt = 0; rt < 2; ++rt)
#pragma unroll
    for (int jt = 0; jt < 8; ++jt) sf[rt][jt] = (f32x4){0.f, 0.f, 0.f, 0.f};

  const u16* abase = ab + h * 128 * 64;
#pragma unroll
  for (int jt = 0; jt < 8; ++jt)
#pragma unroll
    for (int kk = 0; kk < 2; ++kk) {
      bf16x8 bfr = *(const bf16x8*)&abase[(size_t)(jt * 16 + li) * 64 + kk * 32 + lg * 8];
      sf[0][jt] = MFMA16(qf[0][kk], bfr, sf[0][jt]);
      sf[1][jt] = MFMA16(qf[1][kk], bfr, sf[1][jt]);
    }
  float inv[2][4];
#pragma unroll
  for (int rt = 0; rt < 2; ++rt)
#pragma unroll
    for (int r = 0; r < 4; ++r) {
      float cm = sf[rt][0][r];
#pragma unroll
      for (int jt = 1; jt < 8; ++jt) cm = fmaxf(cm, sf[rt][jt][r]);
#pragma unroll
      for (int off = 1; off < 16; off <<= 1) cm = fmaxf(cm, __shfl_xor(cm, off));
      float ss = 0.f;
#pragma unroll
      for (int jt = 0; jt < 8; ++jt) {
        float p = exp2f(sf[rt][jt][r] - cm);
        sf[rt][jt][r] = p;
        ss += p;
      }
#pragma unroll
      for (int off = 1; off < 16; off <<= 1) ss += __shfl_xor(ss, off);
      inv[rt][r] = 1.f / ss;
    }
#pragma unroll
  for (int rt = 0; rt < 2; ++rt)
#pragma unroll
    for (int jt = 0; jt < 8; ++jt)
#pragma unroll
      for (int r = 0; r < 4; ++r)
        p_lds[w * 32 + rt * 16 + lg * 4 + r][jt * 16 + li] = f2bf(sf[rt][jt][r]);

  f32x4 O[2][4];
#pragma unroll
  for (int rt = 0; rt < 2; ++rt)
#pragma unroll
    for (int dt = 0; dt < 4; ++dt) O[rt][dt] = (f32x4){0.f, 0.f, 0.f, 0.f};

  const u16* obase = out1t + (size_t)bh * 64 * 128;
#pragma unroll
  for (int ks = 0; ks < 4; ++ks) {
    bf16x8 pa0 = *(const bf16x8*)&p_lds[w * 32 + li][ks * 32 + lg * 8];
    bf16x8 pa1 = *(const bf16x8*)&p_lds[w * 32 + 16 + li][ks * 32 + lg * 8];
#pragma unroll
    for (int dt = 0; dt < 4; ++dt) {
      bf16x8 bv = *(const bf16x8*)&obase[(size_t)(dt * 16 + li) * 128 + ks * 32 + lg * 8];
      O[0][dt] = MFMA16(pa0, bv, O[0][dt]);
      O[1][dt] = MFMA16(pa1, bv, O[1][dt]);
    }
  }
#pragma unroll
  for (int rt = 0; rt < 2; ++rt)
#pragma unroll
    for (int dt = 0; dt < 4; ++dt)
#pragma unroll
      for (int r = 0; r < 4; ++r) {
        int nn = n0 + w * 32 + rt * 16 + lg * 4 + r;
        int col = h * 64 + dt * 16 + li;
        out2[((size_t)b * 4096 + nn) * 1024 + col] = f2bf(O[rt][dt][r] * inv[rt][r]);
      }
}

// ---------------- launch ----------------
extern "C" void kernel_launch(void* const* d_in, const int* in_sizes, int n_in,
                              void* d_out, int out_size, void* d_ws, size_t ws_size,
                              hipStream_t stream) {
  const float* x = (const float*)d_in[0];
  const float* Wqkv = (const float*)d_in[1];
  const float* agent = (const float*)d_in[2];
  const float* Wout = (const float*)d_in[3];
  float* out = (float*)d_out;

  char* ws = (char*)d_ws;
  u16* x_bf  = (u16*)(ws + 0);
  u16* wqkvT = (u16*)(ws + 33554432);
  u16* woutT = (u16*)(ws + 39845888);
  u16* a_bf  = (u16*)(ws + 41943040);
  u16* qb    = (u16*)(ws + 42205184);
  u16* kb    = (u16*)(ws + 75759616);
  u16* vt    = (u16*)(ws + 142868480);
  float* pO  = (float*)(ws + 176422912);
  float* pM  = (float*)(ws + 193200128);
  float* pL  = (float*)(ws + 193724416);
  u16* out1t = (u16*)(ws + 194248704);
  u16* out2  = x_bf;

  (void)hipFuncSetAttribute((const void*)gemm256<0>, hipFuncAttributeMaxDynamicSharedMemorySize, 131072);
  (void)hipFuncSetAttribute((const void*)gemm256<1>, hipFuncAttributeMaxDynamicSharedMemorySize, 131072);

  prep<<<9728, 256, 0, stream>>>(x, x_bf, Wqkv, wqkvT, Wout, woutT, agent, a_bf);
  gemm256<0><<<768, 512, 131072, stream>>>(x_bf, wqkvT, 16384, 3072, 1024, qb, kb, vt, nullptr);
  ak_flash<<<512, 256, 0, stream>>>(kb, vt, a_bf, pO, pM, pL);
  ak_combine<<<512, 128, 0, stream>>>(pO, pM, pL, out1t);
  qa_fused<<<2048, 256, 0, stream>>>(qb, out1t, a_bf, out2);
  gemm256<1><<<256, 512, 131072, stream>>>(out2, woutT, 16384, 1024, 1024, nullptr, nullptr, nullptr, out);
}